// Round 7
// baseline (370.160 us; speedup 1.0000x reference)
//
#include <hip/hip_runtime.h>

// ---------------------------------------------------------------------------
// DensityMatrixMLP: out[b] = (L Lt) / trace(L Lt),  L = tril(relu(x@W1+b1)@W2+b2)
// B=131072, IN=256, HID=128, TRIL=136, D=16.
//
// R7 (91us): interleaved m-tiles, clean traffic, but occupancy pinned at 36.5%.
// Root cause (unified VGPR/AGPR file): acc1[2][8]=64 AGPR + acc2 ~80 AGPR
// static -> ~144 total regs -> 3 waves/SIMD. Latency-bound at 3 waves/SIMD;
// R2/R6/R7 all ~37-42% occupancy for the same reason.
// R8: per-mt split of the WHOLE pipeline halves peak AGPR (max(32,36)).
// R4/R5 showed this structure spills via GVN/CSE merging the two iterations'
// identical weight-fragment loads -> fix: LAUNDER the weight base offset per
// iteration (asm volatile "+v" on a zero offset) so addresses are symbolically
// distinct and CSE is impossible. Weight reloads hit L2 (FETCH unchanged).
// Diet: bf groups of 4, 1-step x prefetch, tril map recomputed per mt.
// Target ~90-110 total regs -> 4-5 waves/SIMD. One LDS region/wave (20480 B,
// in-order DS pipe ordering verified by R2/R4/R6).
// ---------------------------------------------------------------------------

typedef _Float16 h8 __attribute__((ext_vector_type(8)));
typedef float    f4 __attribute__((ext_vector_type(4)));
typedef int      i2 __attribute__((ext_vector_type(2)));

#define BATCH_N 131072
#define IN_DIM  256
#define HID     128
#define TRILN   136
#define BM      128      // batch rows per block (4 waves x 2 sequential m-tiles)
#define NT1     8        // 128/16 n-tiles, GEMM1
#define KS1     8        // 256/32 k-steps, GEMM1
#define NT2     9        // ceil(136/16) n-tiles, GEMM2 (padded with zeros)
#define KS2     4        // 128/32 k-steps, GEMM2
#define HSTR    136      // h LDS row stride (halves) inside the wave region
#define LVSTR   160      // v LDS row stride (halves): 16 tril rows padded to
                         // 4-half multiples -> every L-row starts 8B-aligned
#define WREG    2560     // halves per wave region: 16 rows x LVSTR
#define PW1_N   (KS1*NT1*64*8)   // 32768 halves = 64 KB
#define PW2_N   (KS2*NT2*64*8)   // 18432 halves = 36 KB

#define FENCE() __builtin_amdgcn_sched_barrier(0)

// offset (halves) of tril row i inside a batch row's LVSTR region:
// rows padded to 4*ceil((i+1)/4); closed form via group g=i>>2.
__device__ __forceinline__ int rowoff(int i) {
    int g = i >> 2;
    return 4 * (g + 1) * (2 * g + (i & 3));   // 0,4,8,12,16,24,...,144
}

// ---------------------------------------------------------------------------
// Prelude: pack W1/W2 into MFMA B-fragment order, fp16.
// ---------------------------------------------------------------------------
__global__ void pack_weights(const float* __restrict__ W1,
                             const float* __restrict__ W2,
                             _Float16* __restrict__ pw1,
                             _Float16* __restrict__ pw2) {
    int gid = blockIdx.x * blockDim.x + threadIdx.x;
    if (gid < PW1_N) {
        int j = gid & 7, l = (gid >> 3) & 63, f = gid >> 9;
        int ks = f >> 3, nt = f & 7;
        int k = ks * 32 + (l >> 4) * 8 + j;
        int n = nt * 16 + (l & 15);
        pw1[gid] = (_Float16)W1[k * HID + n];
    } else if (gid < PW1_N + PW2_N) {
        int g = gid - PW1_N;
        int j = g & 7, l = (g >> 3) & 63, f = g >> 9;
        int ks = f / NT2, nt = f - ks * NT2;
        int k = ks * 32 + (l >> 4) * 8 + j;
        int col = nt * 16 + (l & 15);
        pw2[g] = (col < TRILN) ? (_Float16)W2[k * TRILN + col] : (_Float16)0.0f;
    }
}

__device__ __forceinline__ h8 cvt_h8(f4 lo, f4 hi) {
    h8 r;
    r[0] = (_Float16)lo[0]; r[1] = (_Float16)lo[1];
    r[2] = (_Float16)lo[2]; r[3] = (_Float16)lo[3];
    r[4] = (_Float16)hi[0]; r[5] = (_Float16)hi[1];
    r[6] = (_Float16)hi[2]; r[7] = (_Float16)hi[3];
    return r;
}

// ---------------------------------------------------------------------------
// Fused kernel: 256 threads (4 waves), 128 batch rows/block, NO runtime barrier.
// ---------------------------------------------------------------------------
__global__ __launch_bounds__(256, 4) void fused_mlp(
        const float* __restrict__ x, const float* __restrict__ b1,
        const float* __restrict__ b2, const _Float16* __restrict__ pw1,
        const _Float16* __restrict__ pw2, float* __restrict__ out) {
    __shared__ _Float16 smem[4 * WREG] __attribute__((aligned(16)));  // 20480 B

    const int tid  = threadIdx.x;
    const int w    = tid >> 6;
    const int lane = tid & 63;
    const int q    = lane >> 4;
    const int lm   = lane & 15;
    const int b0   = blockIdx.x * BM;

    _Float16* reg0 = smem + w * WREG;    // this wave's single region

    const int ro_lm = rowoff(lm);
    const f4 zero = (f4){0.f, 0.f, 0.f, 0.f};

    // frag masks: element j of the LL^T frag is L[lm][q*8+j], valid iff q*8+j <= lm
    int msk[4];
    {
        int n = lm - q * 8 + 1;
        #pragma unroll
        for (int p = 0; p < 4; ++p) {
            int c2 = n - 2 * p; c2 = c2 < 0 ? 0 : (c2 > 2 ? 2 : c2);
            msk[p] = (c2 == 2) ? ~0 : ((c2 == 1) ? 0xFFFF : 0);
        }
    }

    #pragma unroll
    for (int mt = 0; mt < 2; ++mt) {
        // ---- launder weight bases: a zero offset the compiler can't prove
        // zero. Each mt iteration gets a DISTINCT opaque value -> the two
        // iterations' fragment loads can never CSE-merge (the R4/R5 spill).
        unsigned zo1 = 0, zo2 = 0;
        asm volatile("" : "+v"(zo1));
        asm volatile("" : "+v"(zo2));
        const _Float16* pw1m = pw1 + zo1;
        const _Float16* pw2m = pw2 + zo2;

        const float* xr = x + (size_t)(b0 + mt * 64 + w * 16 + lm) * IN_DIM + q * 8;

        // ---------------- GEMM1: h = relu(x @ W1 + b1), 16 rows ----------------
        f4 acc[NT1];
        #pragma unroll
        for (int nt = 0; nt < NT1; ++nt) acc[nt] = (f4){0.f, 0.f, 0.f, 0.f};

        {
            f4 cl = *(const f4*)xr, ch = *(const f4*)(xr + 4);
            #pragma unroll
            for (int ks = 0; ks < KS1; ++ks) {
                h8 af = cvt_h8(cl, ch);
                if (ks + 1 < KS1) {  // 1-step x prefetch (8 regs in flight)
                    cl = *(const f4*)(xr + (ks + 1) * 32);
                    ch = *(const f4*)(xr + (ks + 1) * 32 + 4);
                }
                #pragma unroll
                for (int g = 0; g < 2; ++g) {   // nt in groups of 4: bf = 16 VGPR
                    h8 bf[4];
                    #pragma unroll
                    for (int j = 0; j < 4; ++j)
                        bf[j] = *(const h8*)(pw1m + ((ks * NT1 + g * 4 + j) * 64 + lane) * 8);
                    #pragma unroll
                    for (int j = 0; j < 4; ++j)
                        acc[g * 4 + j] = __builtin_amdgcn_mfma_f32_16x16x32_f16(
                            af, bf[j], acc[g * 4 + j], 0, 0, 0);
                }
            }
        }

        FENCE();   // phase boundary

        // ---- bias + relu + store h (own wave's region -> in-order DS pipe) ----
        #pragma unroll
        for (int nt = 0; nt < NT1; ++nt) {
            float b1v = b1[nt * 16 + lm];
            #pragma unroll
            for (int r = 0; r < 4; ++r) {
                float hv = fmaxf(acc[nt][r] + b1v, 0.f);
                reg0[(q * 4 + r) * HSTR + nt * 16 + lm] = (_Float16)hv;
            }
        }

        FENCE();   // h scheduled before GEMM2 loads

        // ---------------- GEMM2: v = h @ W2 ----------------
        f4 acc2[NT2];
        #pragma unroll
        for (int nt = 0; nt < NT2; ++nt) acc2[nt] = (f4){0.f, 0.f, 0.f, 0.f};
        #pragma unroll
        for (int ks = 0; ks < KS2; ++ks) {
            h8 ha = *(const h8*)(reg0 + lm * HSTR + ks * 32 + q * 8);
            #pragma unroll
            for (int nt = 0; nt < NT2; ++nt) {
                h8 bf2 = *(const h8*)(pw2m + ((ks * NT2 + nt) * 64 + lane) * 8);
                acc2[nt] = __builtin_amdgcn_mfma_f32_16x16x32_f16(ha, bf2, acc2[nt], 0, 0, 0);
            }
        }

        FENCE();   // epilogue doesn't hoist into GEMM2

        // ---- bias2 + per-lane tril mapping (recomputed per mt: keeps these
        //      ~20 regs out of the GEMM1 phase) ----
        float b2v[NT2];
        int voff[NT2]; bool vok[NT2];
        #pragma unroll
        for (int nt = 0; nt < NT2; ++nt) {
            int c = nt * 16 + lm;
            vok[nt] = (c < TRILN);
            int cc = vok[nt] ? c : 0;
            int i = (int)((sqrtf(8.0f * (float)cc + 1.0f) - 1.0f) * 0.5f);
            int k = cc - (i * (i + 1)) / 2;
            voff[nt] = rowoff(i) + k;
            b2v[nt] = vok[nt] ? b2[c] : 0.f;
        }

        // ---- trace partials, reduce across the 16-lane row group ----
        float rinv[4];
        #pragma unroll
        for (int r = 0; r < 4; ++r) {
            float s = 0.f;
            #pragma unroll
            for (int nt = 0; nt < NT2; ++nt) {
                float v = acc2[nt][r] + b2v[nt];
                s += v * v;
            }
            s += __shfl_xor(s, 1); s += __shfl_xor(s, 2);
            s += __shfl_xor(s, 4); s += __shfl_xor(s, 8);
            rinv[r] = 1.0f / s;
        }

        // ---- scatter v (fp16) into padded-tril layout (overlays h; WAR is
        //      within-wave through the in-order DS pipe) ----
        #pragma unroll
        for (int r = 0; r < 4; ++r) {
            int base = (q * 4 + r) * LVSTR;
            #pragma unroll
            for (int nt = 0; nt < NT2; ++nt)
                if (vok[nt])
                    reg0[base + voff[nt]] = (_Float16)(acc2[nt][r] + b2v[nt]);
        }

        FENCE();   // scatter scheduled before LL^T frag reads

        // ---- LL^T via MFMA: A-frag == B-frag, one frag per batch row ----
        // D symmetric: lane's d[sr] = D[q*4+sr][lm] = D[lm][q*4+sr] -> the 4
        // values are consecutive cols of row lm -> one dwordx4 store per row.
        #pragma unroll
        for (int tq = 0; tq < 4; ++tq)
            #pragma unroll
            for (int r4 = 0; r4 < 4; ++r4) {
                int t = tq * 4 + r4;
                const _Float16* rp = reg0 + t * LVSTR + ro_lm + q * 8;
                i2 lo = *(const i2*)rp;
                i2 hi = *(const i2*)(rp + 4);
                h8 frag;
                ((i2*)&frag)[0] = (i2){lo.x & msk[0], lo.y & msk[1]};
                ((i2*)&frag)[1] = (i2){hi.x & msk[2], hi.y & msk[3]};
                f4 d = __builtin_amdgcn_mfma_f32_16x16x32_f16(frag, frag, zero, 0, 0, 0);
                float riv = __uint_as_float(
                    __builtin_amdgcn_readlane(__float_as_uint(rinv[r4]), tq * 16));
                f4 dv = d * riv;
                *(f4*)(out + (size_t)(b0 + mt * 64 + w * 16 + t) * 256 + lm * 16 + q * 4) = dv;
            }

        FENCE();   // mt boundary
    }
}

extern "C" void kernel_launch(void* const* d_in, const int* in_sizes, int n_in,
                              void* d_out, int out_size, void* d_ws, size_t ws_size,
                              hipStream_t stream) {
    const float* x  = (const float*)d_in[0];
    const float* W1 = (const float*)d_in[1];
    const float* b1 = (const float*)d_in[2];
    const float* W2 = (const float*)d_in[3];
    const float* b2 = (const float*)d_in[4];
    float* out = (float*)d_out;

    _Float16* pw1 = (_Float16*)d_ws;            // 64 KB
    _Float16* pw2 = pw1 + PW1_N;                // 36 KB  (needs ws_size >= 100 KB)

    pack_weights<<<(PW1_N + PW2_N + 255) / 256, 256, 0, stream>>>(W1, W2, pw1, pw2);
    fused_mlp<<<BATCH_N / BM, 256, 0, stream>>>(x, b1, b2, pw1, pw2, out);
}

// Round 8
// 279.568 us; speedup vs baseline: 1.3240x; 1.3240x over previous
//
#include <hip/hip_runtime.h>

// ---------------------------------------------------------------------------
// DensityMatrixMLP: out[b] = (L Lt) / trace(L Lt),  L = tril(relu(x@W1+b1)@W2+b2)
// B=131072, IN=256, HID=128, TRIL=136, D=16.
//
// Session history: best = R7 91us (interleaved mts, clean). All sequential-
// two-body variants (R3b/R4/R5/R8) spill ~300MB scratch regardless of fences
// or address laundering -> structure abandoned.
// Occupancy analysis: launch_bounds(256,4) caps regs at 128; R2/R6/R7 all
// measure 37-42% occupancy = 3-4 waves/SIMD (reg-limited: 64-72 AGPR acc +
// ~64 arch). Kernel is latency-bound (all pipes <13%, L3-warm x doesn't
// help) -> waves/SIMD IS the lever.
// R9: single-mt body (R6, proven clean) + real AGPR diet -> 5 waves/SIMD:
//   - GEMM1: acc[8]=32 AGPR, bf in groups of 4 (16v), 1-deep x prefetch (8v)
//   - GEMM2: hoist 4 ha LDS reads to regs (16v; h dead -> scatter overlay
//     stays safe), then TWO n-chunks (nt 0-4 / 5-8), acc2 peak 20 AGPR,
//     per-chunk bias + trace-partial ps[] + scatter. Same per-output math.
//   - __launch_bounds__(256,5): reg cap ~102, forces the 5-wave target.
// Abort check next round: WRITE_SIZE >> 137MB means the cap spilled.
// ---------------------------------------------------------------------------

typedef _Float16 h8 __attribute__((ext_vector_type(8)));
typedef float    f4 __attribute__((ext_vector_type(4)));
typedef int      i2 __attribute__((ext_vector_type(2)));

#define BATCH_N 131072
#define IN_DIM  256
#define HID     128
#define TRILN   136
#define BM      64       // batch rows per block = 4 waves x ONE 16-row m-tile
#define NT1     8        // 128/16 n-tiles, GEMM1
#define KS1     8        // 256/32 k-steps, GEMM1
#define NT2     9        // ceil(136/16) n-tiles, GEMM2 (padded with zeros)
#define KS2     4        // 128/32 k-steps, GEMM2
#define HSTR    136      // h LDS row stride (halves) inside the wave region
#define LVSTR   160      // v LDS row stride (halves): 16 tril rows padded to
                         // 4-half multiples -> every L-row starts 8B-aligned
#define WREG    2560     // halves per wave region: 16 rows x LVSTR
#define PW1_N   (KS1*NT1*64*8)   // 32768 halves = 64 KB
#define PW2_N   (KS2*NT2*64*8)   // 18432 halves = 36 KB

#define FENCE() __builtin_amdgcn_sched_barrier(0)

// offset (halves) of tril row i inside a batch row's LVSTR region:
// rows padded to 4*ceil((i+1)/4); closed form via group g=i>>2.
__device__ __forceinline__ int rowoff(int i) {
    int g = i >> 2;
    return 4 * (g + 1) * (2 * g + (i & 3));   // 0,4,8,12,16,24,...,144
}

// ---------------------------------------------------------------------------
// Prelude: pack W1/W2 into MFMA B-fragment order, fp16.
// ---------------------------------------------------------------------------
__global__ void pack_weights(const float* __restrict__ W1,
                             const float* __restrict__ W2,
                             _Float16* __restrict__ pw1,
                             _Float16* __restrict__ pw2) {
    int gid = blockIdx.x * blockDim.x + threadIdx.x;
    if (gid < PW1_N) {
        int j = gid & 7, l = (gid >> 3) & 63, f = gid >> 9;
        int ks = f >> 3, nt = f & 7;
        int k = ks * 32 + (l >> 4) * 8 + j;
        int n = nt * 16 + (l & 15);
        pw1[gid] = (_Float16)W1[k * HID + n];
    } else if (gid < PW1_N + PW2_N) {
        int g = gid - PW1_N;
        int j = g & 7, l = (g >> 3) & 63, f = g >> 9;
        int ks = f / NT2, nt = f - ks * NT2;
        int k = ks * 32 + (l >> 4) * 8 + j;
        int col = nt * 16 + (l & 15);
        pw2[g] = (col < TRILN) ? (_Float16)W2[k * TRILN + col] : (_Float16)0.0f;
    }
}

__device__ __forceinline__ h8 cvt_h8(f4 lo, f4 hi) {
    h8 r;
    r[0] = (_Float16)lo[0]; r[1] = (_Float16)lo[1];
    r[2] = (_Float16)lo[2]; r[3] = (_Float16)lo[3];
    r[4] = (_Float16)hi[0]; r[5] = (_Float16)hi[1];
    r[6] = (_Float16)hi[2]; r[7] = (_Float16)hi[3];
    return r;
}

// ---------------------------------------------------------------------------
// Fused kernel: 256 threads (4 waves), 64 batch rows/block, NO runtime barrier.
// ---------------------------------------------------------------------------
__global__ __launch_bounds__(256, 5) void fused_mlp(
        const float* __restrict__ x, const float* __restrict__ b1,
        const float* __restrict__ b2, const _Float16* __restrict__ pw1,
        const _Float16* __restrict__ pw2, float* __restrict__ out) {
    __shared__ _Float16 smem[4 * WREG] __attribute__((aligned(16)));  // 20480 B

    const int tid  = threadIdx.x;
    const int w    = tid >> 6;
    const int lane = tid & 63;
    const int q    = lane >> 4;
    const int lm   = lane & 15;
    const int rb   = blockIdx.x * BM + w * 16;   // this wave's first batch row

    _Float16* reg0 = smem + w * WREG;            // this wave's region

    const float* xr = x + (size_t)(rb + lm) * IN_DIM + q * 8;

    // ---------------- GEMM1: h = relu(x @ W1 + b1), 16 rows ----------------
    f4 acc[NT1];
    #pragma unroll
    for (int nt = 0; nt < NT1; ++nt) acc[nt] = (f4){0.f, 0.f, 0.f, 0.f};

    {
        f4 cl = *(const f4*)xr, ch = *(const f4*)(xr + 4);
        #pragma unroll
        for (int ks = 0; ks < KS1; ++ks) {
            h8 af = cvt_h8(cl, ch);
            if (ks + 1 < KS1) {  // 1-deep x prefetch (8 regs)
                cl = *(const f4*)(xr + (ks + 1) * 32);
                ch = *(const f4*)(xr + (ks + 1) * 32 + 4);
            }
            #pragma unroll
            for (int g = 0; g < 2; ++g) {   // bf in groups of 4: 16 VGPR
                h8 bf[4];
                #pragma unroll
                for (int j = 0; j < 4; ++j)
                    bf[j] = *(const h8*)(pw1 + ((ks * NT1 + g * 4 + j) * 64 + lane) * 8);
                #pragma unroll
                for (int j = 0; j < 4; ++j)
                    acc[g * 4 + j] = __builtin_amdgcn_mfma_f32_16x16x32_f16(
                        af, bf[j], acc[g * 4 + j], 0, 0, 0);
            }
        }
    }

    FENCE();   // phase boundary

    // ---- bias + relu + store h (own wave's region -> in-order DS pipe) ----
    #pragma unroll
    for (int nt = 0; nt < NT1; ++nt) {
        float b1v = b1[nt * 16 + lm];
        #pragma unroll
        for (int r = 0; r < 4; ++r) {
            float hv = fmaxf(acc[nt][r] + b1v, 0.f);
            reg0[(q * 4 + r) * HSTR + nt * 16 + lm] = (_Float16)hv;
        }
    }

    FENCE();   // h writes scheduled before the ha reads below

    // ---- hoist all h fragment reads into registers (16 VGPR); h is then
    //      dead in LDS, so the per-chunk scatter below can overlay it ----
    h8 ha[KS2];
    #pragma unroll
    for (int ks = 0; ks < KS2; ++ks)
        ha[ks] = *(const h8*)(reg0 + lm * HSTR + ks * 32 + q * 8);

    FENCE();

    // ---------------- GEMM2 in two n-chunks: acc2 peak = 20 AGPR ----------
    float ps[4] = {0.f, 0.f, 0.f, 0.f};   // trace partials, carried across chunks
    #pragma unroll
    for (int c = 0; c < 2; ++c) {
        const int NTC = c ? (NT2 - 5) : 5;   // 5 then 4
        const int ntb = c * 5;

        f4 acc2[5];
        #pragma unroll
        for (int nt = 0; nt < 5; ++nt) acc2[nt] = (f4){0.f, 0.f, 0.f, 0.f};

        #pragma unroll
        for (int ks = 0; ks < KS2; ++ks)
            #pragma unroll
            for (int nt = 0; nt < NTC; ++nt) {
                h8 bf2 = *(const h8*)(pw2 + ((ks * NT2 + ntb + nt) * 64 + lane) * 8);
                acc2[nt] = __builtin_amdgcn_mfma_f32_16x16x32_f16(ha[ks], bf2, acc2[nt], 0, 0, 0);
            }

        // per-chunk: bias2 + trace partials + scatter into padded-tril layout
        #pragma unroll
        for (int nt = 0; nt < NTC; ++nt) {
            int col = (ntb + nt) * 16 + lm;
            bool ok = (col < TRILN);
            int cc = ok ? col : 0;
            int i = (int)((sqrtf(8.0f * (float)cc + 1.0f) - 1.0f) * 0.5f);
            int k = cc - (i * (i + 1)) / 2;
            int vo = rowoff(i) + k;
            float bv = ok ? b2[col] : 0.f;
            #pragma unroll
            for (int r = 0; r < 4; ++r) {
                float v = acc2[nt][r] + bv;
                ps[r] += v * v;                      // cols>=136 contribute 0
                if (ok)
                    reg0[(q * 4 + r) * LVSTR + vo] = (_Float16)v;
            }
        }
    }

    FENCE();   // scatter scheduled before LL^T frag reads

    // ---- reduce trace partials across the 16-lane row group ----
    float rinv[4];
    #pragma unroll
    for (int r = 0; r < 4; ++r) {
        float s = ps[r];
        s += __shfl_xor(s, 1); s += __shfl_xor(s, 2);
        s += __shfl_xor(s, 4); s += __shfl_xor(s, 8);
        rinv[r] = 1.0f / s;
    }

    // frag masks: element j of the LL^T frag is L[lm][q*8+j], valid iff q*8+j <= lm
    int msk[4];
    {
        int n = lm - q * 8 + 1;
        #pragma unroll
        for (int p = 0; p < 4; ++p) {
            int c2 = n - 2 * p; c2 = c2 < 0 ? 0 : (c2 > 2 ? 2 : c2);
            msk[p] = (c2 == 2) ? ~0 : ((c2 == 1) ? 0xFFFF : 0);
        }
    }
    const int ro_lm = rowoff(lm);
    const f4 zero = (f4){0.f, 0.f, 0.f, 0.f};

    // ---- LL^T via MFMA: A-frag == B-frag, one frag per batch row ----
    // D symmetric: lane's d[sr] = D[q*4+sr][lm] = D[lm][q*4+sr] -> the 4
    // values are consecutive cols of row lm -> one dwordx4 store per row.
    #pragma unroll
    for (int tq = 0; tq < 4; ++tq)
        #pragma unroll
        for (int r4 = 0; r4 < 4; ++r4) {
            int t = tq * 4 + r4;
            const _Float16* rp = reg0 + t * LVSTR + ro_lm + q * 8;
            i2 lo = *(const i2*)rp;
            i2 hi = *(const i2*)(rp + 4);
            h8 frag;
            ((i2*)&frag)[0] = (i2){lo.x & msk[0], lo.y & msk[1]};
            ((i2*)&frag)[1] = (i2){hi.x & msk[2], hi.y & msk[3]};
            f4 d = __builtin_amdgcn_mfma_f32_16x16x32_f16(frag, frag, zero, 0, 0, 0);
            float riv = __uint_as_float(
                __builtin_amdgcn_readlane(__float_as_uint(rinv[r4]), tq * 16));
            f4 dv = d * riv;
            *(f4*)(out + (size_t)(rb + t) * 256 + lm * 16 + q * 4) = dv;
        }
}

extern "C" void kernel_launch(void* const* d_in, const int* in_sizes, int n_in,
                              void* d_out, int out_size, void* d_ws, size_t ws_size,
                              hipStream_t stream) {
    const float* x  = (const float*)d_in[0];
    const float* W1 = (const float*)d_in[1];
    const float* b1 = (const float*)d_in[2];
    const float* W2 = (const float*)d_in[3];
    const float* b2 = (const float*)d_in[4];
    float* out = (float*)d_out;

    _Float16* pw1 = (_Float16*)d_ws;            // 64 KB
    _Float16* pw2 = pw1 + PW1_N;                // 36 KB  (needs ws_size >= 100 KB)

    pack_weights<<<(PW1_N + PW2_N + 255) / 256, 256, 0, stream>>>(W1, W2, pw1, pw2);
    fused_mlp<<<BATCH_N / BM, 256, 0, stream>>>(x, b1, b2, pw1, pw2, out);
}